// Round 5
// baseline (85.853 us; speedup 1.0000x reference)
//
#include <hip/hip_runtime.h>
#include <hip/hip_bf16.h>
#include <stdint.h>

// SpanNERDecoder: B=4,S=512,D=768,MAX_LEN=10,LEN_EMB=25,C=9, N=S*10=5120
// Inputs fp32/int32 (reference dtypes; fp32 confirmed: bf16-read NaN'd in R1
// and the runtime bit-pattern detector chose fp32 in R3/R4).
// Output fp32 (reference output dtype; writing bf16 produced the exact
// half-matched/half-zero error signature seen in R2-R4).
// One wave per (b, s0): the 10 spans starting at s0 share a running max-pool
// (lens within a start group are nondecreasing: min(j+1, S-s0)).
constexpr int kB = 4, kS = 512, kD = 768, kMaxLen = 10, kLenEmb = 25, kC = 9;
constexpr int kN = kS * kMaxLen;

__global__ __launch_bounds__(256) void span_ner_kernel(
    const float* __restrict__ emb,      // B*S*D
    const int* __restrict__ starts,     // (B,N) or (N,) broadcast rows
    const int* __restrict__ lens,       // (B,N) or (N,) broadcast rows
    const float* __restrict__ len_tab,  // MAX_LEN*LEN_EMB
    const float* __restrict__ W,        // (D+LEN_EMB)*C row-major
    const float* __restrict__ bias,     // C
    float* __restrict__ out)            // B*N*C fp32
{
  // lenAdd[L][c] = bias[c] + sum_e len_tab[L][e] * W[768+e][c]  (90 values)
  __shared__ float lenAdd[kMaxLen][kC];
  const int t = threadIdx.x;
  if (t < kMaxLen * kC) {
    const int L = t / kC, c = t % kC;
    float s = bias[c];
    #pragma unroll
    for (int e = 0; e < kLenEmb; ++e)
      s = fmaf(len_tab[L * kLenEmb + e], W[(kD + e) * kC + c], s);
    lenAdd[L][c] = s;
  }
  __syncthreads();

  const int lane = t & 63;
  const int wid  = blockIdx.x * 4 + (t >> 6);  // 0..2047
  const int b    = wid >> 9;
  const int s0   = wid & 511;

  // W slice for this lane: features [lane*12, lane*12+12), all 9 labels —
  // 108 contiguous floats at lane*108 (432B offset, 16-aligned).
  float w[108];
  {
    const float4* wp = (const float4*)(W + lane * 108);
    #pragma unroll
    for (int i = 0; i < 27; ++i) {
      float4 u = wp[i];
      w[4 * i + 0] = u.x;
      w[4 * i + 1] = u.y;
      w[4 * i + 2] = u.z;
      w[4 * i + 3] = u.w;
    }
  }

  float pool[12];
  #pragma unroll
  for (int k = 0; k < 12; ++k) pool[k] = -INFINITY;

  // Broadcast rows are identical across b -> index by n only (also correct
  // if the harness materialized just the (N,) base vector).
  const int base_n = s0 * kMaxLen;
  const int start  = starts[base_n];  // wave-uniform
  const float* rowbase = emb + (size_t)(b * kS + start) * kD + lane * 12;

  int rl = 0;  // rows folded into the running max so far
  for (int j = 0; j < kMaxLen; ++j) {
    int ln = lens[base_n + j];  // wave-uniform, nondecreasing in j
    ln = min(max(ln, 1), kMaxLen);
    while (rl < ln) {
      const float4* rp = (const float4*)(rowbase + (size_t)rl * kD);
      #pragma unroll
      for (int i = 0; i < 3; ++i) {
        float4 u = rp[i];
        pool[4 * i + 0] = fmaxf(pool[4 * i + 0], u.x);
        pool[4 * i + 1] = fmaxf(pool[4 * i + 1], u.y);
        pool[4 * i + 2] = fmaxf(pool[4 * i + 2], u.z);
        pool[4 * i + 3] = fmaxf(pool[4 * i + 3], u.w);
      }
      ++rl;
    }

    // dot(pool, W[lane*12 : lane*12+12, :]) -> 9 partials per lane
    float acc[kC];
    #pragma unroll
    for (int c = 0; c < kC; ++c) acc[c] = 0.f;
    #pragma unroll
    for (int k = 0; k < 12; ++k)
      #pragma unroll
      for (int c = 0; c < kC; ++c)
        acc[c] = fmaf(pool[k], w[k * kC + c], acc[c]);

    // 64-lane butterfly reduce (all lanes end with full sums)
    #pragma unroll
    for (int off = 32; off > 0; off >>= 1)
      #pragma unroll
      for (int c = 0; c < kC; ++c)
        acc[c] += __shfl_xor(acc[c], off, 64);

    // lane c (c<9) stores logit c as fp32
    float v = acc[0];
    #pragma unroll
    for (int c = 1; c < kC; ++c) v = (lane == c) ? acc[c] : v;
    if (lane < kC) {
      v += lenAdd[ln - 1][lane];
      out[(size_t)(b * kN + base_n + j) * kC + lane] = v;
    }
  }
}

extern "C" void kernel_launch(void* const* d_in, const int* in_sizes, int n_in,
                              void* d_out, int out_size, void* d_ws, size_t ws_size,
                              hipStream_t stream) {
  const float* emb     = (const float*)d_in[0];
  const int*   starts  = (const int*)d_in[1];
  const int*   lens    = (const int*)d_in[2];
  const float* len_tab = (const float*)d_in[3];
  const float* W       = (const float*)d_in[4];
  const float* bias    = (const float*)d_in[5];
  float*       out     = (float*)d_out;

  dim3 grid(kB * kS / 4);  // 512 blocks x 256 threads = 2048 waves
  span_ner_kernel<<<grid, dim3(256), 0, stream>>>(emb, starts, lens, len_tab, W,
                                                  bias, out);
}